// Round 1
// baseline (121.809 us; speedup 1.0000x reference)
//
#include <hip/hip_runtime.h>

#define HW 80
#define NPIX (HW * HW)

// One block handles 256 pixels of one batch. It first (redundantly, per block)
// compacts the batch's masked pixel coordinates into LDS, then each thread
// computes the hard min squared distance from its pixel to the masked set
// (exact equivalent of the T=0.01 softmin: non-minimal weights are <=
// exp(-100) ~ 3.7e-44, negligible vs 2% tolerance), multiplies by pred, and
// the block atomically accumulates scale * blockSum into out[0].
__global__ __launch_bounds__(256) void soft_hausdorff_kernel(
    const float* __restrict__ pred,
    const float* __restrict__ target,
    float* __restrict__ out,
    float scale)   // 1/B
{
    __shared__ int s_coords[NPIX];   // packed x | (y<<16)
    __shared__ int s_cnt;
    __shared__ float s_red[4];

    const int tid = threadIdx.x;
    const int b = blockIdx.y;
    if (tid == 0) s_cnt = 0;
    __syncthreads();

    const float* tgt = target + b * NPIX;
    const int lane = tid & 63;
    const int wid = tid >> 6;

    // ---- compact masked coords into LDS (ballot + 1 atomic per wave) ----
    for (int base = 0; base < NPIX; base += 256) {
        int i = base + tid;
        bool flag = tgt[i] > 0.5f;
        unsigned long long m = __ballot(flag);
        int wcnt = __popcll(m);
        int wbase = 0;
        if (lane == 0) wbase = atomicAdd(&s_cnt, wcnt);
        wbase = __shfl(wbase, 0);
        if (flag) {
            int pos = wbase + __popcll(m & ((1ull << lane) - 1ull));
            int x = i % HW;
            int y = i / HW;
            s_coords[pos] = x | (y << 16);
        }
    }
    __syncthreads();
    const int K = s_cnt;

    // ---- per-thread min over the masked set ----
    const int i = blockIdx.x * 256 + tid;
    const int xi = i % HW;
    const int yi = i / HW;
    int minD = 0x7fffffff;
    #pragma unroll 4
    for (int k = 0; k < K; ++k) {
        int pc = s_coords[k];            // LDS broadcast (all lanes same addr)
        int dx = (pc & 0xffff) - xi;
        int dy = (pc >> 16) - yi;
        int d = dx * dx + dy * dy;
        minD = min(minD, d);
    }
    float val = (K > 0) ? pred[b * NPIX + i] * (float)minD : 0.0f;

    // ---- block reduction ----
    #pragma unroll
    for (int off = 32; off > 0; off >>= 1)
        val += __shfl_down(val, off);
    if (lane == 0) s_red[wid] = val;
    __syncthreads();
    if (wid == 0) {
        float v = (lane < 4) ? s_red[lane] : 0.0f;
        v += __shfl_down(v, 2);
        v += __shfl_down(v, 1);
        if (lane == 0 && K > 0) atomicAdd(out, scale * v);
    }
}

extern "C" void kernel_launch(void* const* d_in, const int* in_sizes, int n_in,
                              void* d_out, int out_size, void* d_ws, size_t ws_size,
                              hipStream_t stream) {
    const float* pred = (const float*)d_in[0];
    const float* target = (const float*)d_in[1];
    float* out = (float*)d_out;

    const int B = in_sizes[0] / NPIX;   // 2 for the reference shapes
    const float scale = 1.0f / (float)B;

    // d_out is poisoned with 0xAA before every launch; zero it first.
    hipMemsetAsync(d_out, 0, sizeof(float), stream);

    dim3 grid(NPIX / 256, B);
    soft_hausdorff_kernel<<<grid, 256, 0, stream>>>(pred, target, out, scale);
}

// Round 2
// 62.110 us; speedup vs baseline: 1.9612x; 1.9612x over previous
//
#include <hip/hip_runtime.h>

#define HW 80
#define NPIX (HW * HW)
#define INF1D 200          // > any real 1-D distance (max 79); 200^2 + dx^2 fits int easily
#define EMPTY_THRESH 20000 // real max sq dist = 79^2+79^2 = 12482 < 20000 < 200^2

// Exact separable Euclidean distance transform:
//   minD(x,y) = min_{x'} [ (x-x')^2 + g(y,x')^2 ],
//   g(y,x')   = 1-D distance from y to nearest masked row in column x'.
// One block handles 256 pixels of one batch; each block redundantly computes
// the full column transform for its batch (trivial: 80 cols x 160 steps).
// Hard min == T=0.01 softmin to within exp(-100) (validated: absmax 0.0).
__global__ __launch_bounds__(256) void soft_hausdorff_kernel(
    const float* __restrict__ pred,
    const float* __restrict__ target,
    float* __restrict__ out,
    float scale)   // 1/B
{
    __shared__ int a[NPIX];  // 0/INF1D mask, then in-place 1-D column distances

    const int tid = threadIdx.x;
    const int b = blockIdx.y;
    const float* tgt = target + b * NPIX;

    // ---- phase 1: load mask as 0 / INF1D (coalesced) ----
    #pragma unroll
    for (int base = 0; base < NPIX; base += 256) {
        int i = base + tid;
        a[i] = (tgt[i] > 0.5f) ? 0 : INF1D;
    }
    __syncthreads();

    // ---- phase 2: per-column forward/backward 1-D distance scan ----
    if (tid < HW) {
        const int x = tid;
        int d = INF1D;
        #pragma unroll
        for (int y = 0; y < HW; ++y) {
            int idx = y * HW + x;
            d = min(a[idx], d + 1);
            a[idx] = d;
        }
        d = INF1D;
        #pragma unroll
        for (int y = HW - 1; y >= 0; --y) {
            int idx = y * HW + x;
            d = min(a[idx], d + 1);
            a[idx] = d;
        }
    }
    __syncthreads();

    // ---- phase 3: per-pixel min over 80 columns ----
    const int i = blockIdx.x * 256 + tid;      // pixel within batch
    const int yi = i / HW;
    const int xi = i % HW;
    const int rowBase = yi * HW;
    int minD = 1 << 28;
    #pragma unroll 8
    for (int xp = 0; xp < HW; ++xp) {
        int g = a[rowBase + xp];               // mostly LDS broadcast within a wave
        int dx = xi - xp;
        minD = min(minD, g * g + dx * dx);
    }
    // empty target set => all columns INF => minD >= 40000 => contribute 0
    float val = (minD < EMPTY_THRESH) ? pred[b * NPIX + i] * (float)minD : 0.0f;

    // ---- block reduction + global accumulate ----
    const int lane = tid & 63;
    const int wid = tid >> 6;
    __shared__ float s_red[4];
    #pragma unroll
    for (int off = 32; off > 0; off >>= 1)
        val += __shfl_down(val, off);
    if (lane == 0) s_red[wid] = val;
    __syncthreads();
    if (wid == 0) {
        float v = (lane < 4) ? s_red[lane] : 0.0f;
        v += __shfl_down(v, 2);
        v += __shfl_down(v, 1);
        if (lane == 0) atomicAdd(out, scale * v);
    }
}

extern "C" void kernel_launch(void* const* d_in, const int* in_sizes, int n_in,
                              void* d_out, int out_size, void* d_ws, size_t ws_size,
                              hipStream_t stream) {
    const float* pred = (const float*)d_in[0];
    const float* target = (const float*)d_in[1];
    float* out = (float*)d_out;

    const int B = in_sizes[0] / NPIX;   // 2 for the reference shapes
    const float scale = 1.0f / (float)B;

    // d_out is poisoned with 0xAA before every launch; zero it first.
    hipMemsetAsync(d_out, 0, sizeof(float), stream);

    dim3 grid(NPIX / 256, B);
    soft_hausdorff_kernel<<<grid, 256, 0, stream>>>(pred, target, out, scale);
}

// Round 3
// 59.966 us; speedup vs baseline: 2.0313x; 1.0357x over previous
//
#include <hip/hip_runtime.h>

#define HW 80
#define NPIX (HW * HW)          // 6400
#define INF1D 200               // > max real 1-D distance (79)
#define EMPTY_THRESH 20000      // max real sq dist 79^2+79^2=12482 < 20000 < INF1D^2=40000

// Exact separable EDT, equivalent to the T=0.01 softmin (non-minimal softmax
// weights <= exp(-100); validated absmax 0.0 in R1/R2).
//   minD(x,y) = min_{x'} [ (x-x')^2 + g2(y,x') ],  g2 = squared 1-D column dist.
// R3: phase-2 column scan held in registers (kills the ds_read->min->ds_write
// dependency chain), g^2 precomputed, phase-3 uses int4 LDS loads + 4
// independent min accumulators.
__global__ __launch_bounds__(256) void soft_hausdorff_kernel(
    const float* __restrict__ pred,
    const float* __restrict__ target,
    float* __restrict__ out,
    float scale)   // 1/B
{
    __shared__ int a[NPIX];  // 0/INF1D mask, then overwritten in-place with g^2

    const int tid = threadIdx.x;
    const int b = blockIdx.y;

    // ---- phase 1: vectorized mask load (coalesced float4 -> int4 LDS) ----
    const float4* tgt4 = (const float4*)(target + b * NPIX);
    for (int i = tid; i < NPIX / 4; i += 256) {   // 1600 int4s, 7 iters (last partial)
        float4 t = tgt4[i];
        int4 m;
        m.x = (t.x > 0.5f) ? 0 : INF1D;
        m.y = (t.y > 0.5f) ? 0 : INF1D;
        m.z = (t.z > 0.5f) ? 0 : INF1D;
        m.w = (t.w > 0.5f) ? 0 : INF1D;
        ((int4*)a)[i] = m;
    }
    __syncthreads();

    // ---- phase 2: per-column fwd/bwd scan, register-resident ----
    if (tid < HW) {
        const int x = tid;
        int m[HW];
        #pragma unroll
        for (int y = 0; y < HW; ++y) m[y] = a[y * HW + x];   // independent loads
        int d = INF1D;
        #pragma unroll
        for (int y = 0; y < HW; ++y) { d = min(m[y], d + 1); m[y] = d; }
        d = INF1D;
        #pragma unroll
        for (int y = HW - 1; y >= 0; --y) {
            d = min(m[y], d + 1);
            a[y * HW + x] = d * d;               // store g^2 (columns disjoint)
        }
    }
    __syncthreads();

    // ---- phase 3: per-pixel min over 80 columns, int4 loads, 4 chains ----
    const int i = blockIdx.x * 256 + tid;        // pixel within batch
    const int yi = i / HW;
    const int xi = i % HW;
    const int4* g2row = (const int4*)(a + yi * HW);  // 320B rows, 16B aligned
    int m0 = 1 << 28, m1 = 1 << 28, m2 = 1 << 28, m3 = 1 << 28;
    #pragma unroll
    for (int q = 0; q < HW / 4; ++q) {
        int4 g = g2row[q];
        int dx0 = xi - 4 * q;
        int dx1 = dx0 - 1, dx2 = dx0 - 2, dx3 = dx0 - 3;
        m0 = min(m0, dx0 * dx0 + g.x);
        m1 = min(m1, dx1 * dx1 + g.y);
        m2 = min(m2, dx2 * dx2 + g.z);
        m3 = min(m3, dx3 * dx3 + g.w);
    }
    int minD = min(min(m0, m1), min(m2, m3));
    // empty target set => all g^2 = 40000 => minD >= 40000 => contribute 0
    float val = (minD < EMPTY_THRESH) ? pred[b * NPIX + i] * (float)minD : 0.0f;

    // ---- block reduction + global accumulate ----
    const int lane = tid & 63;
    const int wid = tid >> 6;
    __shared__ float s_red[4];
    #pragma unroll
    for (int off = 32; off > 0; off >>= 1)
        val += __shfl_down(val, off);
    if (lane == 0) s_red[wid] = val;
    __syncthreads();
    if (wid == 0) {
        float v = (lane < 4) ? s_red[lane] : 0.0f;
        v += __shfl_down(v, 2);
        v += __shfl_down(v, 1);
        if (lane == 0) atomicAdd(out, scale * v);
    }
}

extern "C" void kernel_launch(void* const* d_in, const int* in_sizes, int n_in,
                              void* d_out, int out_size, void* d_ws, size_t ws_size,
                              hipStream_t stream) {
    const float* pred = (const float*)d_in[0];
    const float* target = (const float*)d_in[1];
    float* out = (float*)d_out;

    const int B = in_sizes[0] / NPIX;   // 2 for the reference shapes
    const float scale = 1.0f / (float)B;

    // d_out is poisoned with 0xAA before every launch; zero it first.
    hipMemsetAsync(d_out, 0, sizeof(float), stream);

    dim3 grid(NPIX / 256, B);
    soft_hausdorff_kernel<<<grid, 256, 0, stream>>>(pred, target, out, scale);
}